// Round 1
// baseline (107.834 us; speedup 1.0000x reference)
//
#include <hip/hip_runtime.h>
#include <math.h>

#define NV 1000000
#define NC 4000000
#define NGROUP (NC / 4)   // 4 clauses per thread-iteration
#define TPB 256
#define NBLK 2048

// literal value = sigmoid(sign ? x : -x)  ==  sign ? sigmoid(x) : 1-sigmoid(x)
__device__ __forceinline__ float lit_val(const float* __restrict__ logits, int idx, int sign) {
    float x = logits[idx];
    x = sign ? x : -x;
    return 1.0f / (1.0f + __expf(-x));
}

__global__ void sat_init(float* out_scalars) {
    // out_scalars[0] = all_satisfied (min, seeded +inf); [1] = n_satisfied (sum, seeded 0)
    out_scalars[0] = INFINITY;
    out_scalars[1] = 0.0f;
}

__global__ __launch_bounds__(TPB) void sat_main(
    const float* __restrict__ logits,
    const int4*  __restrict__ vars4,   // [3*NGROUP]
    const int4*  __restrict__ signs4,  // [3*NGROUP]
    float* __restrict__ out)           // [0,NV) assignments | [NV,NV+NC) sats | 2 scalars
{
    const int tid = blockIdx.x * TPB + threadIdx.x;
    const int nthreads = gridDim.x * TPB;

    // ---- Part A: assignments = sigmoid(logits), float4-vectorized ----
    const float4* l4 = (const float4*)logits;
    float4* o4 = (float4*)out;
    for (int i = tid; i < NV / 4; i += nthreads) {
        float4 v = l4[i];
        float4 r;
        r.x = 1.0f / (1.0f + __expf(-v.x));
        r.y = 1.0f / (1.0f + __expf(-v.y));
        r.z = 1.0f / (1.0f + __expf(-v.z));
        r.w = 1.0f / (1.0f + __expf(-v.w));
        o4[i] = r;
    }

    // ---- Part B: clause satisfactions (4 clauses / iteration) ----
    float minv = INFINITY;
    int cnt = 0;
    float4* sats4 = (float4*)(out + NV);
    for (int g = tid; g < NGROUP; g += nthreads) {
        int4 a  = vars4[3 * g], b  = vars4[3 * g + 1], c  = vars4[3 * g + 2];
        int4 sa = signs4[3 * g], sb = signs4[3 * g + 1], sc = signs4[3 * g + 2];
        float4 r;
        r.x = fmaxf(fmaxf(lit_val(logits, a.x, sa.x), lit_val(logits, a.y, sa.y)),
                    lit_val(logits, a.z, sa.z));
        r.y = fmaxf(fmaxf(lit_val(logits, a.w, sa.w), lit_val(logits, b.x, sb.x)),
                    lit_val(logits, b.y, sb.y));
        r.z = fmaxf(fmaxf(lit_val(logits, b.z, sb.z), lit_val(logits, b.w, sb.w)),
                    lit_val(logits, c.x, sc.x));
        r.w = fmaxf(fmaxf(lit_val(logits, c.y, sc.y), lit_val(logits, c.z, sc.z)),
                    lit_val(logits, c.w, sc.w));
        sats4[g] = r;
        minv = fminf(minv, fminf(fminf(r.x, r.y), fminf(r.z, r.w)));
        cnt += (r.x > 0.5f) + (r.y > 0.5f) + (r.z > 0.5f) + (r.w > 0.5f);
    }

    // ---- Block reduction: min + count ----
    float fcnt = (float)cnt;
    #pragma unroll
    for (int off = 32; off > 0; off >>= 1) {
        minv = fminf(minv, __shfl_down(minv, off));
        fcnt += __shfl_down(fcnt, off);
    }
    __shared__ float smin[TPB / 64];
    __shared__ float scnt[TPB / 64];
    const int wave = threadIdx.x >> 6, lane = threadIdx.x & 63;
    if (lane == 0) { smin[wave] = minv; scnt[wave] = fcnt; }
    __syncthreads();
    if (threadIdx.x == 0) {
        float m = smin[0], s = scnt[0];
        #pragma unroll
        for (int w = 1; w < TPB / 64; ++w) { m = fminf(m, smin[w]); s += scnt[w]; }
        // all sat values are > 0, so uint ordering == float ordering
        atomicMin((unsigned int*)(out + NV + NC), __float_as_uint(m));
        atomicAdd(out + NV + NC + 1, s);   // integer-valued adds: exact, order-independent
    }
}

extern "C" void kernel_launch(void* const* d_in, const int* in_sizes, int n_in,
                              void* d_out, int out_size, void* d_ws, size_t ws_size,
                              hipStream_t stream) {
    const float* logits = (const float*)d_in[0];
    const int4*  vars4  = (const int4*)d_in[1];
    const int4*  signs4 = (const int4*)d_in[2];
    float* out = (float*)d_out;

    sat_init<<<1, 1, 0, stream>>>(out + NV + NC);
    sat_main<<<NBLK, TPB, 0, stream>>>(logits, vars4, signs4, out);
}